// Round 2
// baseline (104.048 us; speedup 1.0000x reference)
//
#include <hip/hip_runtime.h>
#include <math.h>

#define DIM 4096
#define ROWS 2048
#define SB 72   // LDS image row stride in halves: %8==0 -> 16B-aligned ds_read_b128
                // frag loads. Row stride 144B: frag-read addr mod 128B = 16*((n+q)&7)
                // -> 8 lanes per 16B slot = wave64-b128 minimum (conflict-free);
                // b64 writes land on 8*((2n+q)&15) -> 4 lanes/slot, also min.
#define GS 68   // gt_lds row stride in floats: %4==0 -> 16B-aligned float4 reads;
                // read bank = (4(n+q)+16I)%32 -> 8 words/bank = b128 minimum.

typedef _Float16 half8  __attribute__((ext_vector_type(8)));
typedef _Float16 half4  __attribute__((ext_vector_type(4)));
typedef float    float4e __attribute__((ext_vector_type(4)));

// Load the 8 MFMA fragments of the 64x64 image with the contraction dim
// CONTIGUOUS: frag[F][Kt][j] = img[16F+n][32Kt+8q+j] -> one ds_read_b128 each.
// Serves as:
//   stage-R: A-frag(I=F):  A[m=16F+n][k=32Kt+8q+j]      (A-layout m=lane&15, k=8q+j)
//   stage-L: B-frag(J=F):  B[k][n'=16F+n] = S[n'][k]    (B-layout n=lane&15, k=8q+j)
__device__ __forceinline__ void load_frags(const _Float16* __restrict__ img,
                                           int n, int q, half8 frag[4][2]) {
#pragma unroll
    for (int F = 0; F < 4; ++F)
#pragma unroll
        for (int Kt = 0; Kt < 2; ++Kt)
            frag[F][Kt] = *(const half8*)(img + (16 * F + n) * SB + 32 * Kt + 8 * q);
}

// stage-R: C = S * H   (image row-major as A; H fragments as B, valid because
// H is symmetric: Hf[J][Kt][j] = H[16J+n][32Kt+8q+j] = H[32Kt+8q+j][16J+n]).
__device__ __forceinline__ void mul_H_right(const half8 frag[4][2], const half8 Hf[4][2],
                                            float4e acc[4][4]) {
#pragma unroll
    for (int I = 0; I < 4; ++I)
#pragma unroll
        for (int J = 0; J < 4; ++J) {
            float4e c = {0.0f, 0.0f, 0.0f, 0.0f};
            c = __builtin_amdgcn_mfma_f32_16x16x32_f16(frag[I][0], Hf[J][0], c, 0, 0, 0);
            c = __builtin_amdgcn_mfma_f32_16x16x32_f16(frag[I][1], Hf[J][1], c, 0, 0, 0);
            acc[I][J] = c;
        }
}

// stage-L: C = H * S^T  (H as A; image col-major as B).
__device__ __forceinline__ void mul_H_left(const half8 frag[4][2], const half8 Hf[4][2],
                                           float4e acc[4][4]) {
#pragma unroll
    for (int I = 0; I < 4; ++I)
#pragma unroll
        for (int J = 0; J < 4; ++J) {
            float4e c = {0.0f, 0.0f, 0.0f, 0.0f};
            c = __builtin_amdgcn_mfma_f32_16x16x32_f16(Hf[I][0], frag[J][0], c, 0, 0, 0);
            c = __builtin_amdgcn_mfma_f32_16x16x32_f16(Hf[I][1], frag[J][1], c, 0, 0, 0);
            acc[I][J] = c;
        }
}

// Write acc (C-layout: row=16I+4q+r, col=16J+n [m89]) TRANSPOSED to the image:
// img[col][row] -> image = C^T. 4 contiguous rows -> one 8B half4 write.
__device__ __forceinline__ void img_write_T(_Float16* __restrict__ img,
                                            int n, int q, const float4e acc[4][4]) {
#pragma unroll
    for (int I = 0; I < 4; ++I)
#pragma unroll
        for (int J = 0; J < 4; ++J) {
            half4 h;
            h[0] = (_Float16)acc[I][J][0];
            h[1] = (_Float16)acc[I][J][1];
            h[2] = (_Float16)acc[I][J][2];
            h[3] = (_Float16)acc[I][J][3];
            *(half4*)(img + (16 * J + n) * SB + 16 * I + 4 * q) = h;
        }
}

// One wave per row. FWHT_4096 = H64 (x) H64: with V[a][b] = v[64a+b],
// FWHT(v) = H.V.H. Alternating-side schedule (all LDS frag reads b128):
//   S0 = V                         (row-major img0)
//   R:  C1 = V.H        -> S1 = (V.H)^T   = H.V^T
//   L:  C2 = H.S1^T     = H.V.H = Z       (FWHT1 done, in acc)
//   acc *= G (block-shared transposed g image in LDS, r-contiguous reads)
//   -> S2 = Z'^T
//   R:  C3 = Z'^T.H     -> S3 = (Z'^T.H)^T = H.Z'
//   L:  C4 = H.S3^T     = H.Z'^T.H = Y^T   (FWHT2 done)
//   out[e] = s1[e] * Y^T element, e = 1024J+64n+16I+4q+r.
// g = g_mu + softplus(g_rho)*eps is computed IN-BLOCK (16 elem/thread,
// float4-coalesced inputs, same libm math as the old pre-kernel) into a
// transposed padded LDS image -> no second kernel dispatch in the graph.
// Wave-private img: NO barriers for the FWHT; ONE __syncthreads before the
// g-multiply makes the cooperative g image visible.
__global__ void __launch_bounds__(256, 2)
whvi_mfma(const float* __restrict__ x, const float* __restrict__ s1,
          const float* __restrict__ s2,
          const float* __restrict__ eps, const float* __restrict__ g_mu,
          const float* __restrict__ g_rho, float* __restrict__ out) {
    const int t    = threadIdx.x;
    const int lane = t & 63;
    const int wid  = t >> 6;
    const int row  = blockIdx.x * 4 + wid;     // 512 blocks x 4 waves = 2048 rows
    const int n = lane & 15, q = lane >> 4;

    __shared__ __align__(16) _Float16 ldsimg[4 * 64 * SB];   // 36 KB
    __shared__ __align__(16) float    gt_lds[64 * GS];       // 17 KB (54.3 KB tot)
    _Float16* __restrict__ img = ldsimg + wid * 64 * SB;     // wave-private

    // ---- issue g-input loads FIRST (12 b128): the in-order vmcnt wait for
    // them then leaves the 32 x/s2 loads still outstanding.
    const float4e* __restrict__ ev4 = (const float4e*)eps;
    const float4e* __restrict__ mv4 = (const float4e*)g_mu;
    const float4e* __restrict__ rv4 = (const float4e*)g_rho;
    float4e ev[4], mv[4], rv[4];
#pragma unroll
    for (int v = 0; v < 4; ++v) ev[v] = ev4[4 * t + v];
#pragma unroll
    for (int v = 0; v < 4; ++v) mv[v] = mv4[4 * t + v];
#pragma unroll
    for (int v = 0; v < 4; ++v) rv[v] = rv4[4 * t + v];

    // ---- bulk row loads (32 b128 in flight)
    const float4e* __restrict__ xr  = (const float4e*)(x + (size_t)row * DIM);
    const float4e* __restrict__ s2v = (const float4e*)s2;
    float4e xv[16], sv[16];
#pragma unroll
    for (int r = 0; r < 16; ++r) xv[r] = xr[64 * r + lane];
#pragma unroll
    for (int r = 0; r < 16; ++r) sv[r] = s2v[64 * r + lane];

    // ---- g compute + transposed scatter (overlaps x-load HBM latency).
    // Thread t owns e = 16t..16t+15 (a = e>>6 = t>>2 const; b = e&63 spans
    // 16(t&3)..+15, no row crossing). gt_lds[b*GS + a] = g[64a + b].
    // Scatter bank = (68k + t>>2)%32 -> 16 banks x 4 lanes, one-time cost.
    {
        const int ga = t >> 2, gb0 = (t & 3) << 4;
#pragma unroll
        for (int v = 0; v < 4; ++v)
#pragma unroll
            for (int i = 0; i < 4; ++i) {
                float gval = fmaf(log1pf(expf(rv[v][i])), ev[v][i], mv[v][i]);
                gt_lds[(gb0 + 4 * v + i) * GS + ga] = gval;
            }
    }

    // ---- H fragments (A-layout: m=lane&15, k=8q+j [m120]); VALU, also
    // overlaps the outstanding x loads.
    half8 Hf[4][2];
#pragma unroll
    for (int I = 0; I < 4; ++I)
#pragma unroll
        for (int Kt = 0; Kt < 2; ++Kt) {
            half8 h;
#pragma unroll
            for (int j = 0; j < 8; ++j) {
                int rr = 16 * I + n, cc = 32 * Kt + 8 * q + j;
                h[j] = (__popc(rr & cc) & 1) ? (_Float16)(-1.0f) : (_Float16)(1.0f);
            }
            Hf[I][Kt] = h;
        }

    // ---- IMG0 = V = s2*x: element e=256r+4*lane+i -> img[(4r+q)*SB + 4n + i]
#pragma unroll
    for (int r = 0; r < 16; ++r) {
        float4e p = xv[r] * sv[r];
        half4 h;
        h[0] = (_Float16)p[0]; h[1] = (_Float16)p[1];
        h[2] = (_Float16)p[2]; h[3] = (_Float16)p[3];
        *(half4*)(img + (4 * r + q) * SB + 4 * n) = h;
    }

    half8   frag[4][2];
    float4e acc[4][4];

    load_frags(img, n, q, frag);
    mul_H_right(frag, Hf, acc);          // C1 = V.H
    img_write_T(img, n, q, acc);         // S1 = H.V^T   (in-order DS: safe reuse)

    load_frags(img, n, q, frag);
    mul_H_left(frag, Hf, acc);           // C2 = Z = H.V.H

    __syncthreads();                     // g image from all 4 waves now visible

    // ---- g multiply: acc holds Z (row=16I+4q+r, col=16J+n);
    // G[row][col] = g[64row+col] = gt_lds[(16J+n)*GS + 16I+4q+r], r-contig b128.
#pragma unroll
    for (int I = 0; I < 4; ++I)
#pragma unroll
        for (int J = 0; J < 4; ++J) {
            const float4e gg = *(const float4e*)(gt_lds + (16 * J + n) * GS + 16 * I + 4 * q);
            acc[I][J] *= gg;
        }

    img_write_T(img, n, q, acc);         // S2 = Z'^T
    load_frags(img, n, q, frag);
    mul_H_right(frag, Hf, acc);          // C3 = Z'^T.H
    img_write_T(img, n, q, acc);         // S3 = H.Z'
    load_frags(img, n, q, frag);
    mul_H_left(frag, Hf, acc);           // C4 = Y^T

    // ---- s1 scale + store: e = 1024J + 64n + 16I + 4q (+r): b128, line-covered
    float* __restrict__ orow = out + (size_t)row * DIM;
#pragma unroll
    for (int I = 0; I < 4; ++I)
#pragma unroll
        for (int J = 0; J < 4; ++J) {
            const int e = 1024 * J + 64 * n + 16 * I + 4 * q;
            const float4e sg = *(const float4e*)(s1 + e);
            *(float4e*)(orow + e) = acc[I][J] * sg;
        }
}

extern "C" void kernel_launch(void* const* d_in, const int* in_sizes, int n_in,
                              void* d_out, int out_size, void* d_ws, size_t ws_size,
                              hipStream_t stream) {
    // setup_inputs order: x, epsilon, s1, s2, g_mu, g_rho
    const float* x     = (const float*)d_in[0];
    const float* eps   = (const float*)d_in[1];
    const float* s1    = (const float*)d_in[2];
    const float* s2    = (const float*)d_in[3];
    const float* g_mu  = (const float*)d_in[4];
    const float* g_rho = (const float*)d_in[5];
    float* out = (float*)d_out;
    (void)d_ws; (void)ws_size;

    // Single fused dispatch: g is computed in-block (no pre-kernel, no
    // inter-kernel dependency drain in the captured graph).
    whvi_mfma<<<ROWS / 4, 256, 0, stream>>>(x, s1, s2, eps, g_mu, g_rho, out);
}